// Round 18
// baseline (249.501 us; speedup 1.0000x reference)
//
#include <hip/hip_runtime.h>
#include <math.h>

#define N_NODES 100000
#define N_EDGES 1600000
#define F_INN   256
#define HID     128
#define NCLS    47

#define SCAN_CHUNK 1024
#define N_SBLOCKS ((N_NODES + SCAN_CHUNK - 1) / SCAN_CHUNK)  // 98
#define G1_BLOCKS ((N_NODES + 127) / 128)                    // 782
#define CNT_BLOCKS ((N_EDGES / 4 + 255) / 256)               // 1563
#define N_PART 8
#define PART_SZ ((N_NODES + N_PART - 1) / N_PART)            // 12500

typedef __attribute__((ext_vector_type(8))) short bf16x8;
typedef __attribute__((ext_vector_type(4))) float f32x4;
typedef __attribute__((ext_vector_type(2))) float f32x2;
typedef __attribute__((ext_vector_type(4))) int i32x4;

// ---------------- bf16 helpers (RNE) ----------------
__device__ __forceinline__ unsigned bf16pack(float a, float b) {
    unsigned ua = __float_as_uint(a), ub = __float_as_uint(b);
    ua = (ua + 0x7FFFu + ((ua >> 16) & 1u)) >> 16;
    ub = (ub + 0x7FFFu + ((ub >> 16) & 1u)) >> 16;
    return ua | (ub << 16);
}
__device__ __forceinline__ float2 bf16unpack(unsigned v) {
    return make_float2(__uint_as_float(v << 16), __uint_as_float(v & 0xFFFF0000u));
}

// ---------------- fp8 e4m3 (OCP) helpers ------------------------------------
__device__ __forceinline__ unsigned fp8enc(float f) {
    unsigned u = __float_as_uint(f);
    unsigned r = u + 0x7FFFFu + ((u >> 20) & 1u);  // RNE into bit 20
    unsigned exp = (r >> 23) & 0xFFu;
    unsigned s = (u >> 24) & 0x80u;
    if (exp < 121u) return s;                      // flush to +-0
    if (exp > 135u) return s | 0x7Eu;              // saturate (won't occur)
    return s | ((exp - 120u) << 3) | ((r >> 20) & 7u);
}

#if __has_builtin(__builtin_amdgcn_cvt_pk_f32_fp8) && __has_builtin(__builtin_amdgcn_cvt_f32_fp8)
#define HWCVT 1
#endif

// decode 4 fp8 (one u32) -> 4 f32
__device__ __forceinline__ void fp8dec4(unsigned v, float& a, float& b, float& c, float& d) {
#ifdef HWCVT
    f32x2 lo = __builtin_amdgcn_cvt_pk_f32_fp8((int)v, false);
    f32x2 hi = __builtin_amdgcn_cvt_pk_f32_fp8((int)v, true);
    a = lo[0]; b = lo[1]; c = hi[0]; d = hi[1];
#else
    unsigned p0 = v & 0xFFFFu, p1 = v >> 16;
    unsigned m0 = ((p0 & 0x7Fu) << 4) + ((p0 & 0x7F00u) << 12) + 0x3C003C00u;
    unsigned g0 = ((p0 & 0x80u) << 8) | ((p0 & 0x8000u) << 16);
    unsigned b0 = m0 | g0;
    unsigned m1 = ((p1 & 0x7Fu) << 4) + ((p1 & 0x7F00u) << 12) + 0x3C003C00u;
    unsigned g1 = ((p1 & 0x80u) << 8) | ((p1 & 0x8000u) << 16);
    unsigned b1_ = m1 | g1;
    a = __uint_as_float(b0 << 16); b = __uint_as_float(b0 & 0xFFFF0000u);
    c = __uint_as_float(b1_ << 16); d = __uint_as_float(b1_ & 0xFFFF0000u);
#endif
}

// ---------------- CSR build ----------------
__global__ void k_init(int* cnt) {
    int i = blockIdx.x * blockDim.x + threadIdx.x;
    if (i < N_NODES) cnt[i] = 0;
}

__global__ __launch_bounds__(256) void k_scan_part(const int* __restrict__ cnt,
                                                   int* __restrict__ bsum) {
    int b = blockIdx.x, t = threadIdx.x;
    int base = b * SCAN_CHUNK;
    int local = 0;
#pragma unroll
    for (int u = 0; u < 4; u++) {
        int idx = base + u * 256 + t;
        if (idx < N_NODES) local += cnt[idx];
    }
#pragma unroll
    for (int off = 32; off >= 1; off >>= 1) local += __shfl_down(local, off, 64);
    __shared__ int red[4];
    if ((t & 63) == 0) red[t >> 6] = local;
    __syncthreads();
    if (t == 0) bsum[b] = red[0] + red[1] + red[2] + red[3];
}

__global__ void k_scan_top(const int* __restrict__ bsum, int* __restrict__ boff) {
    __shared__ int s[128];
    int t = threadIdx.x;
    int v = (t < N_SBLOCKS) ? bsum[t] : 0;
    s[t] = v;
    __syncthreads();
    for (int off = 1; off < 128; off <<= 1) {
        int u = (t >= off) ? s[t - off] : 0;
        __syncthreads();
        s[t] += u;
        __syncthreads();
    }
    if (t < N_SBLOCKS) boff[t] = s[t] - v;  // exclusive
}

__global__ __launch_bounds__(256) void k_scan_final(const int* __restrict__ cnt,
                                                    const int* __restrict__ boff,
                                                    int* __restrict__ rowptr,
                                                    float* __restrict__ dinv) {
    __shared__ int tsum[256];
    int b = blockIdx.x, t = threadIdx.x;
    int base = b * SCAN_CHUNK + t * 4;
    int c[4];
    int local = 0;
#pragma unroll
    for (int u = 0; u < 4; u++) {
        int idx = base + u;
        c[u] = (idx < N_NODES) ? cnt[idx] : 0;
        local += c[u];
    }
    tsum[t] = local;
    __syncthreads();
    for (int off = 1; off < 256; off <<= 1) {
        int u = (t >= off) ? tsum[t - off] : 0;
        __syncthreads();
        tsum[t] += u;
        __syncthreads();
    }
    int run = boff[b] + tsum[t] - local;
#pragma unroll
    for (int u = 0; u < 4; u++) {
        int idx = base + u;
        if (idx < N_NODES) {
            rowptr[idx] = run;
            dinv[idx] = rsqrtf((float)c[u] + 1.0f);  // +1 self-loop
            run += c[u];
        }
    }
    if (b == 0 && t == 0) rowptr[N_NODES] = N_EDGES;
}

// partitioned scatter: block bid&7 owns nodes [p*PART_SZ, (p+1)*PART_SZ);
// scans whole edge list (NT reads via ext_vector types), writes only its
// partition -> each partition's eidx region (~800KB) gets temporally-local
// writes that combine in (one XCD's) L2. Correct for ANY XCD mapping.
__global__ __launch_bounds__(256) void k_scatter(const int* __restrict__ src,
                                                 const int* __restrict__ dst,
                                                 const int* __restrict__ rowptr,
                                                 const unsigned* __restrict__ rank1,
                                                 int* __restrict__ eidx) {
    int bid = blockIdx.x;
    int part = bid & (N_PART - 1);
    int chunk = bid >> 3;
    int t = chunk * 256 + threadIdx.x;
    if (t >= N_EDGES / 4) return;
    i32x4 d = __builtin_nontemporal_load((const i32x4*)dst + t);
    int lo = part * PART_SZ, hi = lo + PART_SZ;
    bool m0 = (d.x >= lo && d.x < hi);
    bool m1 = (d.y >= lo && d.y < hi);
    bool m2 = (d.z >= lo && d.z < hi);
    bool m3 = (d.w >= lo && d.w < hi);
    if (!(m0 | m1 | m2 | m3)) return;
    i32x4 s = __builtin_nontemporal_load((const i32x4*)src + t);
    unsigned r = __builtin_nontemporal_load(rank1 + t);
    if (m0) eidx[rowptr[d.x] + (int)(r & 0xFFu)] = s.x;
    if (m1) eidx[rowptr[d.y] + (int)((r >> 8) & 0xFFu)] = s.y;
    if (m2) eidx[rowptr[d.z] + (int)((r >> 16) & 0xFFu)] = s.z;
    if (m3) eidx[rowptr[d.w] + (int)(r >> 24)] = s.w;
}

// ---- prep: W1 (256x128 f32) -> MFMA-fragment-ordered bf16 ------------------
__global__ __launch_bounds__(256) void k_prep(const float* __restrict__ W1,
                                              uint4* __restrict__ Wf) {
    int g = blockIdx.x * blockDim.x + threadIdx.x;  // 0..4095
    if (g >= 4096) return;
    int l = g & 63;
    int kst = (g >> 6) & 7;
    int nt = g >> 9;
    int n = nt * 16 + (l & 15);
    int kb = kst * 32 + ((l >> 4) << 3);
    float v[8];
#pragma unroll
    for (int j = 0; j < 8; j++) v[j] = W1[(size_t)(kb + j) * HID + n];
    uint4 o;
    o.x = bf16pack(v[0], v[1]);
    o.y = bf16pack(v[2], v[3]);
    o.z = bf16pack(v[4], v[5]);
    o.w = bf16pack(v[6], v[7]);
    Wf[g] = o;
}

// ---- fused: GEMM1 (MFMA, unscaled fp8 out) || count+rank -------------------
__global__ __launch_bounds__(256) void k_fusedA(const float* __restrict__ X,
                                                const uint4* __restrict__ Wf,
                                                unsigned char* __restrict__ Y8,
                                                const int4* __restrict__ dst4,
                                                int* cnt,
                                                uchar4* __restrict__ rank4) {
    __shared__ __align__(16) unsigned short xs[128 * 32];
    int bid = blockIdx.x;
    int tid = threadIdx.x;

    // role assignment: bids [0, 2*G1): even=gemm1, odd=count; rest=count
    int gemm_b = -1, cnt_b = -1;
    if (bid < 2 * G1_BLOCKS) {
        if (bid & 1) cnt_b = bid >> 1;
        else gemm_b = bid >> 1;
    } else {
        cnt_b = G1_BLOCKS + (bid - 2 * G1_BLOCKS);
    }

    if (cnt_b >= 0) {
        int t = cnt_b * 256 + tid;
        if (t < N_EDGES / 4) {
            int4 d = dst4[t];
            unsigned r0 = atomicAdd(&cnt[d.x], 1);
            unsigned r1 = atomicAdd(&cnt[d.y], 1);
            unsigned r2 = atomicAdd(&cnt[d.z], 1);
            unsigned r3 = atomicAdd(&cnt[d.w], 1);
            rank4[t] = make_uchar4((unsigned char)r0, (unsigned char)r1,
                                   (unsigned char)r2, (unsigned char)r3);
        }
        return;
    }

    // ---- gemm1 role ----
    int lane = tid & 63, w = tid >> 6;
    int wr = w >> 1, wc = w & 1;
    int row0 = gemm_b * 128;

    f32x4 acc[4][4];  // [fm][fn]
#pragma unroll
    for (int i = 0; i < 4; i++)
#pragma unroll
        for (int j = 0; j < 4; j++) acc[i][j] = (f32x4){0.f, 0.f, 0.f, 0.f};

    for (int ks = 0; ks < 8; ks++) {
        int k0 = ks * 32;
#pragma unroll
        for (int u = 0; u < 4; u++) {
            int slot = u * 256 + tid;          // 0..1023
            int r = slot >> 3, c4 = slot & 7;  // row, float4-slot
            int rr = min(row0 + r, N_NODES - 1);
            float4 v = *(const float4*)&X[(size_t)rr * F_INN + k0 + c4 * 4];
            uint2 p;
            p.x = bf16pack(v.x, v.y);
            p.y = bf16pack(v.z, v.w);
            *(uint2*)&xs[r * 32 + c4 * 4] = p;
        }
        bf16x8 bfr[4];
#pragma unroll
        for (int fn = 0; fn < 4; fn++) {
            uint4 t4 = Wf[((wc * 4 + fn) * 8 + ks) * 64 + lane];
            bfr[fn] = *(bf16x8*)&t4;
        }
        __syncthreads();
        bf16x8 afr[4];
#pragma unroll
        for (int fm = 0; fm < 4; fm++) {
            int r = wr * 64 + fm * 16 + (lane & 15);
            afr[fm] = *(const bf16x8*)&xs[r * 32 + ((lane >> 4) << 3)];
        }
#pragma unroll
        for (int fm = 0; fm < 4; fm++)
#pragma unroll
            for (int fn = 0; fn < 4; fn++)
                acc[fm][fn] = __builtin_amdgcn_mfma_f32_16x16x32_bf16(
                    bfr[fn], afr[fm], acc[fm][fn], 0, 0, 0);
        __syncthreads();
    }
    // epilogue: UNSCALED fp8 (dinv applied per-edge in gather1)
#pragma unroll
    for (int fm = 0; fm < 4; fm++) {
        int row = row0 + wr * 64 + fm * 16 + (lane & 15);
        if (row < N_NODES) {
            unsigned char* yrow = Y8 + (size_t)row * 128;
#pragma unroll
            for (int fn = 0; fn < 4; fn++) {
                int col = wc * 64 + fn * 16 + ((lane >> 4) << 2);
                unsigned o = fp8enc(acc[fm][fn][0])
                           | (fp8enc(acc[fm][fn][1]) << 8)
                           | (fp8enc(acc[fm][fn][2]) << 16)
                           | (fp8enc(acc[fm][fn][3]) << 24);
                *(unsigned*)&yrow[col] = o;
            }
        }
    }
}

// ------------- gather1: 2 nodes/wave, per-edge dinv FMA, unroll 8 -----------
__global__ __launch_bounds__(256) void k_gather1(const unsigned* __restrict__ Y32,
                                                 const int* __restrict__ rowptr,
                                                 const int* __restrict__ eidx,
                                                 const float* __restrict__ dinv,
                                                 const float* __restrict__ b1,
                                                 unsigned* __restrict__ Hb) {
    int wid = (blockIdx.x * blockDim.x + threadIdx.x) >> 6;
    int lane = threadIdx.x & 63;
    int half = lane >> 5, sl = lane & 31;
    int node = wid * 2 + half;
    if (node >= N_NODES) return;

    float s = dinv[node];
    float d0, d1, d2, d3;
    fp8dec4(Y32[(size_t)node * 32 + sl], d0, d1, d2, d3);  // self-loop
    float a0 = s * d0, a1 = s * d1, a2 = s * d2, a3 = s * d3;
    int beg = rowptr[node], end = rowptr[node + 1];
    int e = beg;
    int n8 = beg + ((end - beg) & ~7);
    for (; e < n8; e += 8) {
        int j[8];
#pragma unroll
        for (int u = 0; u < 8; u++) j[u] = eidx[e + u];
        unsigned v[8];
        float dv[8];
#pragma unroll
        for (int u = 0; u < 8; u++) {
            v[u] = Y32[(size_t)j[u] * 32 + sl];
            dv[u] = dinv[j[u]];
        }
#pragma unroll
        for (int u = 0; u < 8; u++) {
            fp8dec4(v[u], d0, d1, d2, d3);
            a0 = fmaf(dv[u], d0, a0);
            a1 = fmaf(dv[u], d1, a1);
            a2 = fmaf(dv[u], d2, a2);
            a3 = fmaf(dv[u], d3, a3);
        }
    }
    for (; e < end; e++) {
        int j = eidx[e];
        unsigned v = Y32[(size_t)j * 32 + sl];
        float dvv = dinv[j];
        fp8dec4(v, d0, d1, d2, d3);
        a0 = fmaf(dvv, d0, a0);
        a1 = fmaf(dvv, d1, a1);
        a2 = fmaf(dvv, d2, a2);
        a3 = fmaf(dvv, d3, a3);
    }
    float4 b = ((const float4*)b1)[sl];
    uint2 p;
    p.x = bf16pack(fmaxf(a0 * s + b.x, 0.f), fmaxf(a1 * s + b.y, 0.f));
    p.y = bf16pack(fmaxf(a2 * s + b.z, 0.f), fmaxf(a3 * s + b.w, 0.f));
    *(uint2*)&Hb[(size_t)node * 64 + sl * 2] = p;
}

// ------------- GEMM2: Y2_8 = fp8((H @ W2) * dinv[row]), row stride 64 B -----
__global__ __launch_bounds__(256) void k_gemm2(const unsigned* __restrict__ Hb,
                                               const float* __restrict__ W2,
                                               const float* __restrict__ dinv,
                                               unsigned char* __restrict__ Y2_8) {
    __shared__ __align__(16) float ws[128][48];
    int tid = threadIdx.x;
    for (int idx = tid; idx < 128 * 48; idx += 256) {
        int k = idx / 48, c = idx - k * 48;
        ws[k][c] = (c < NCLS) ? W2[k * NCLS + c] : 0.f;
    }
    __syncthreads();
    int row = blockIdx.x * 256 + tid;
    if (row >= N_NODES) return;
    float4 acc[12];
#pragma unroll
    for (int i = 0; i < 12; i++) acc[i] = make_float4(0.f, 0.f, 0.f, 0.f);
    const uint4* h4 = (const uint4*)(Hb + (size_t)row * 64);
    for (int kq = 0; kq < 16; kq++) {
        uint4 hv = h4[kq];
        float f[8];
        float2 f0 = bf16unpack(hv.x), f1 = bf16unpack(hv.y);
        float2 f2 = bf16unpack(hv.z), f3 = bf16unpack(hv.w);
        f[0] = f0.x; f[1] = f0.y; f[2] = f1.x; f[3] = f1.y;
        f[4] = f2.x; f[5] = f2.y; f[6] = f3.x; f[7] = f3.y;
#pragma unroll
        for (int u = 0; u < 8; u++) {
            float xv = f[u];
            int k = kq * 8 + u;
#pragma unroll
            for (int c = 0; c < 12; c++) {
                float4 w = *(const float4*)&ws[k][c * 4];
                acc[c].x += xv * w.x; acc[c].y += xv * w.y;
                acc[c].z += xv * w.z; acc[c].w += xv * w.w;
            }
        }
    }
    float s = dinv[row];
#pragma unroll
    for (int c = 0; c < 12; c++) {
        unsigned o = fp8enc(acc[c].x * s)
                   | (fp8enc(acc[c].y * s) << 8)
                   | (fp8enc(acc[c].z * s) << 16)
                   | (fp8enc(acc[c].w * s) << 24);
        *(unsigned*)&Y2_8[(size_t)row * 64 + c * 4] = o;
    }
}

// --- gather2 + log_softmax: 4 nodes/wave, 16 lanes/node, unroll 16 ----------
__global__ __launch_bounds__(256) void k_gather2(const unsigned* __restrict__ Y2_32,
                                                 const int* __restrict__ rowptr,
                                                 const int* __restrict__ eidx,
                                                 const float* __restrict__ dinv,
                                                 const float* __restrict__ b2,
                                                 float* __restrict__ Out) {
    int wid = (blockIdx.x * blockDim.x + threadIdx.x) >> 6;
    int lane = threadIdx.x & 63;
    int q = lane >> 4, sl = lane & 15;
    int node = wid * 4 + q;
    if (node >= N_NODES) return;

    float a0, a1, a2, a3;
    fp8dec4(Y2_32[(size_t)node * 16 + sl], a0, a1, a2, a3);  // self (pad lanes gated below)
    int beg = rowptr[node], end = rowptr[node + 1];
    int e = beg;
    int n16 = beg + ((end - beg) & ~15);
    for (; e < n16; e += 16) {
        int j[16];
#pragma unroll
        for (int u = 0; u < 16; u++) j[u] = eidx[e + u];
        unsigned v[16];
#pragma unroll
        for (int u = 0; u < 16; u++) v[u] = Y2_32[(size_t)j[u] * 16 + sl];
#pragma unroll
        for (int u = 0; u < 16; u++) {
            float d0, d1, d2, d3;
            fp8dec4(v[u], d0, d1, d2, d3);
            a0 += d0; a1 += d1; a2 += d2; a3 += d3;
        }
    }
    int n8 = e + ((end - e) & ~7);
    for (; e < n8; e += 8) {
        int j[8];
#pragma unroll
        for (int u = 0; u < 8; u++) j[u] = eidx[e + u];
        unsigned v[8];
#pragma unroll
        for (int u = 0; u < 8; u++) v[u] = Y2_32[(size_t)j[u] * 16 + sl];
#pragma unroll
        for (int u = 0; u < 8; u++) {
            float d0, d1, d2, d3;
            fp8dec4(v[u], d0, d1, d2, d3);
            a0 += d0; a1 += d1; a2 += d2; a3 += d3;
        }
    }
    for (; e < end; e++) {
        unsigned v = Y2_32[(size_t)eidx[e] * 16 + sl];
        float d0, d1, d2, d3;
        fp8dec4(v, d0, d1, d2, d3);
        a0 += d0; a1 += d1; a2 += d2; a3 += d3;
    }
    float s = dinv[node];
    int d0i = sl * 4;
    float v0 = (d0i + 0 < NCLS) ? a0 * s + b2[d0i + 0] : -INFINITY;
    float v1 = (d0i + 1 < NCLS) ? a1 * s + b2[d0i + 1] : -INFINITY;
    float v2 = (d0i + 2 < NCLS) ? a2 * s + b2[d0i + 2] : -INFINITY;
    float v3 = (d0i + 3 < NCLS) ? a3 * s + b2[d0i + 3] : -INFINITY;
    float m = fmaxf(fmaxf(v0, v1), fmaxf(v2, v3));
#pragma unroll
    for (int off = 1; off < 16; off <<= 1) m = fmaxf(m, __shfl_xor(m, off, 16));
    float ex = 0.f;
    ex += (d0i + 0 < NCLS) ? __expf(v0 - m) : 0.f;
    ex += (d0i + 1 < NCLS) ? __expf(v1 - m) : 0.f;
    ex += (d0i + 2 < NCLS) ? __expf(v2 - m) : 0.f;
    ex += (d0i + 3 < NCLS) ? __expf(v3 - m) : 0.f;
#pragma unroll
    for (int off = 1; off < 16; off <<= 1) ex += __shfl_xor(ex, off, 16);
    float l = __logf(ex);
    float* orow = Out + (size_t)node * NCLS;
    if (d0i + 0 < NCLS) orow[d0i + 0] = v0 - m - l;
    if (d0i + 1 < NCLS) orow[d0i + 1] = v1 - m - l;
    if (d0i + 2 < NCLS) orow[d0i + 2] = v2 - m - l;
    if (d0i + 3 < NCLS) orow[d0i + 3] = v3 - m - l;
}

extern "C" void kernel_launch(void* const* d_in, const int* in_sizes, int n_in,
                              void* d_out, int out_size, void* d_ws, size_t ws_size,
                              hipStream_t stream) {
    const float* x   = (const float*)d_in[0];
    const int*   ei  = (const int*)d_in[1];
    const float* W1  = (const float*)d_in[2];
    const float* b1  = (const float*)d_in[3];
    const float* W2  = (const float*)d_in[4];
    const float* b2  = (const float*)d_in[5];
    float* out = (float*)d_out;

    const int* src = ei;             // edge_index[0]
    const int* dst = ei + N_EDGES;   // edge_index[1]

    char* ws = (char*)d_ws;
    unsigned char*  y8   = (unsigned char*) (ws + 0);          // N*128 u8  (12.8 MB)
    unsigned*       hb   = (unsigned*)      (ws + 12800000);   // N*64 u32  (25.6 MB)
    unsigned char*  y2_8 = (unsigned char*) (ws + 38400000);   // N*64 u8   (6.4 MB)
    float*          dinv = (float*)         (ws + 44800000);   // N f32
    int*            cnt  = (int*)           (ws + 45200000);   // N int
    int*            rowptr=(int*)           (ws + 45600000);   // N+1 int
    int*            eidx = (int*)           (ws + 46000016);   // E int (6.4 MB)
    int*            bsum = (int*)           (ws + 52400016);   // 98 int
    int*            boff = (int*)           (ws + 52401040);   // 98 int
    unsigned char*  rank = (unsigned char*) (ws + 52402064);   // E u8 (1.6 MB)
    uint4*          wfrag= (uint4*)         (ws + 54002064);   // 64 KB

    // prologue (cheap): zero counters, pack W1 fragments
    k_init<<<(N_NODES + 255) / 256, 256, 0, stream>>>(cnt);
    k_prep<<<16, 256, 0, stream>>>(W1, wfrag);

    // fused: count+rank (atomic-throughput-bound) || gemm1 (MFMA-bound)
    k_fusedA<<<2 * G1_BLOCKS + (CNT_BLOCKS - G1_BLOCKS), 256, 0, stream>>>(
        x, wfrag, y8, (const int4*)dst, cnt, (uchar4*)rank);

    // scan -> rowptr, dinv
    k_scan_part<<<N_SBLOCKS, 256, 0, stream>>>(cnt, bsum);
    k_scan_top<<<1, 128, 0, stream>>>(bsum, boff);
    k_scan_final<<<N_SBLOCKS, 256, 0, stream>>>(cnt, boff, rowptr, dinv);

    // partitioned scatter: 8 partitions x all chunks
    k_scatter<<<N_PART * CNT_BLOCKS, 256, 0, stream>>>(
        src, dst, rowptr, (const unsigned*)rank, eidx);

    // layer 1 aggregation (per-edge dinv)
    k_gather1<<<((N_NODES + 1) / 2 * 64 + 255) / 256, 256, 0, stream>>>(
        (const unsigned*)y8, rowptr, eidx, dinv, b1, hb);

    // layer 2
    k_gemm2<<<(N_NODES + 255) / 256, 256, 0, stream>>>(hb, W2, dinv, y2_8);
    k_gather2<<<((N_NODES + 3) / 4 * 64 + 255) / 256, 256, 0, stream>>>(
        (const unsigned*)y2_8, rowptr, eidx, dinv, b2, out);
}

// Round 20
// 237.894 us; speedup vs baseline: 1.0488x; 1.0488x over previous
//
#include <hip/hip_runtime.h>
#include <math.h>

#define N_NODES 100000
#define N_EDGES 1600000
#define F_INN   256
#define HID     128
#define NCLS    47

#define SCAN_CHUNK 1024
#define N_SBLOCKS ((N_NODES + SCAN_CHUNK - 1) / SCAN_CHUNK)  // 98
#define G1_BLOCKS ((N_NODES + 127) / 128)                    // 782
#define CNT_BLOCKS ((N_EDGES / 4 + 255) / 256)               // 1563

typedef __attribute__((ext_vector_type(8))) short bf16x8;
typedef __attribute__((ext_vector_type(4))) float f32x4;
typedef __attribute__((ext_vector_type(2))) float f32x2;

// ---------------- bf16 helpers (RNE) ----------------
__device__ __forceinline__ unsigned bf16pack(float a, float b) {
    unsigned ua = __float_as_uint(a), ub = __float_as_uint(b);
    ua = (ua + 0x7FFFu + ((ua >> 16) & 1u)) >> 16;
    ub = (ub + 0x7FFFu + ((ub >> 16) & 1u)) >> 16;
    return ua | (ub << 16);
}
__device__ __forceinline__ float2 bf16unpack(unsigned v) {
    return make_float2(__uint_as_float(v << 16), __uint_as_float(v & 0xFFFF0000u));
}

// ---------------- fp8 e4m3 (OCP) helpers ------------------------------------
__device__ __forceinline__ unsigned fp8enc(float f) {
    unsigned u = __float_as_uint(f);
    unsigned r = u + 0x7FFFFu + ((u >> 20) & 1u);  // RNE into bit 20
    unsigned exp = (r >> 23) & 0xFFu;
    unsigned s = (u >> 24) & 0x80u;
    if (exp < 121u) return s;                      // flush to +-0
    if (exp > 135u) return s | 0x7Eu;              // saturate (won't occur)
    return s | ((exp - 120u) << 3) | ((r >> 20) & 7u);
}

#if __has_builtin(__builtin_amdgcn_cvt_pk_f32_fp8) && __has_builtin(__builtin_amdgcn_cvt_f32_fp8)
#define HWCVT 1
#endif

// decode 4 fp8 (one u32) -> 4 f32
__device__ __forceinline__ void fp8dec4(unsigned v, float& a, float& b, float& c, float& d) {
#ifdef HWCVT
    f32x2 lo = __builtin_amdgcn_cvt_pk_f32_fp8((int)v, false);
    f32x2 hi = __builtin_amdgcn_cvt_pk_f32_fp8((int)v, true);
    a = lo[0]; b = lo[1]; c = hi[0]; d = hi[1];
#else
    unsigned p0 = v & 0xFFFFu, p1 = v >> 16;
    unsigned m0 = ((p0 & 0x7Fu) << 4) + ((p0 & 0x7F00u) << 12) + 0x3C003C00u;
    unsigned g0 = ((p0 & 0x80u) << 8) | ((p0 & 0x8000u) << 16);
    unsigned b0 = m0 | g0;
    unsigned m1 = ((p1 & 0x7Fu) << 4) + ((p1 & 0x7F00u) << 12) + 0x3C003C00u;
    unsigned g1 = ((p1 & 0x80u) << 8) | ((p1 & 0x8000u) << 16);
    unsigned b1_ = m1 | g1;
    a = __uint_as_float(b0 << 16); b = __uint_as_float(b0 & 0xFFFF0000u);
    c = __uint_as_float(b1_ << 16); d = __uint_as_float(b1_ & 0xFFFF0000u);
#endif
}

// ---------------- CSR build ----------------
__global__ void k_init(int* cnt) {
    int i = blockIdx.x * blockDim.x + threadIdx.x;
    if (i < N_NODES) cnt[i] = 0;
}

__global__ __launch_bounds__(256) void k_scan_part(const int* __restrict__ cnt,
                                                   int* __restrict__ bsum) {
    int b = blockIdx.x, t = threadIdx.x;
    int base = b * SCAN_CHUNK;
    int local = 0;
#pragma unroll
    for (int u = 0; u < 4; u++) {
        int idx = base + u * 256 + t;
        if (idx < N_NODES) local += cnt[idx];
    }
#pragma unroll
    for (int off = 32; off >= 1; off >>= 1) local += __shfl_down(local, off, 64);
    __shared__ int red[4];
    if ((t & 63) == 0) red[t >> 6] = local;
    __syncthreads();
    if (t == 0) bsum[b] = red[0] + red[1] + red[2] + red[3];
}

__global__ void k_scan_top(const int* __restrict__ bsum, int* __restrict__ boff) {
    __shared__ int s[128];
    int t = threadIdx.x;
    int v = (t < N_SBLOCKS) ? bsum[t] : 0;
    s[t] = v;
    __syncthreads();
    for (int off = 1; off < 128; off <<= 1) {
        int u = (t >= off) ? s[t - off] : 0;
        __syncthreads();
        s[t] += u;
        __syncthreads();
    }
    if (t < N_SBLOCKS) boff[t] = s[t] - v;  // exclusive
}

__global__ __launch_bounds__(256) void k_scan_final(const int* __restrict__ cnt,
                                                    const int* __restrict__ boff,
                                                    int* __restrict__ rowptr,
                                                    float* __restrict__ dinv) {
    __shared__ int tsum[256];
    int b = blockIdx.x, t = threadIdx.x;
    int base = b * SCAN_CHUNK + t * 4;
    int c[4];
    int local = 0;
#pragma unroll
    for (int u = 0; u < 4; u++) {
        int idx = base + u;
        c[u] = (idx < N_NODES) ? cnt[idx] : 0;
        local += c[u];
    }
    tsum[t] = local;
    __syncthreads();
    for (int off = 1; off < 256; off <<= 1) {
        int u = (t >= off) ? tsum[t - off] : 0;
        __syncthreads();
        tsum[t] += u;
        __syncthreads();
    }
    int run = boff[b] + tsum[t] - local;
#pragma unroll
    for (int u = 0; u < 4; u++) {
        int idx = base + u;
        if (idx < N_NODES) {
            rowptr[idx] = run;
            dinv[idx] = rsqrtf((float)c[u] + 1.0f);  // +1 self-loop
            run += c[u];
        }
    }
    if (b == 0 && t == 0) rowptr[N_NODES] = N_EDGES;
}

// atomic-free scatter, 4 edges/thread (round-16 proven form)
__global__ __launch_bounds__(256) void k_scatter(const int4* __restrict__ src4,
                                                 const int4* __restrict__ dst4,
                                                 const int* __restrict__ rowptr,
                                                 const uchar4* __restrict__ rank4,
                                                 int* __restrict__ eidx) {
    int t = blockIdx.x * blockDim.x + threadIdx.x;
    if (t < N_EDGES / 4) {
        int4 s = src4[t];
        int4 d = dst4[t];
        uchar4 r = rank4[t];
        int p0 = rowptr[d.x] + (int)r.x;
        int p1 = rowptr[d.y] + (int)r.y;
        int p2 = rowptr[d.z] + (int)r.z;
        int p3 = rowptr[d.w] + (int)r.w;
        eidx[p0] = s.x;
        eidx[p1] = s.y;
        eidx[p2] = s.z;
        eidx[p3] = s.w;
    }
}

// ---- prep: W1 (256x128 f32) -> MFMA-fragment-ordered bf16 ------------------
__global__ __launch_bounds__(256) void k_prep(const float* __restrict__ W1,
                                              uint4* __restrict__ Wf) {
    int g = blockIdx.x * blockDim.x + threadIdx.x;  // 0..4095
    if (g >= 4096) return;
    int l = g & 63;
    int kst = (g >> 6) & 7;
    int nt = g >> 9;
    int n = nt * 16 + (l & 15);
    int kb = kst * 32 + ((l >> 4) << 3);
    float v[8];
#pragma unroll
    for (int j = 0; j < 8; j++) v[j] = W1[(size_t)(kb + j) * HID + n];
    uint4 o;
    o.x = bf16pack(v[0], v[1]);
    o.y = bf16pack(v[2], v[3]);
    o.z = bf16pack(v[4], v[5]);
    o.w = bf16pack(v[6], v[7]);
    Wf[g] = o;
}

// ---- fused: GEMM1 (MFMA, unscaled fp8 out) || count+rank -------------------
__global__ __launch_bounds__(256) void k_fusedA(const float* __restrict__ X,
                                                const uint4* __restrict__ Wf,
                                                unsigned char* __restrict__ Y8,
                                                const int4* __restrict__ dst4,
                                                int* cnt,
                                                uchar4* __restrict__ rank4) {
    __shared__ __align__(16) unsigned short xs[128 * 32];
    int bid = blockIdx.x;
    int tid = threadIdx.x;

    // role assignment: bids [0, 2*G1): even=gemm1, odd=count; rest=count
    int gemm_b = -1, cnt_b = -1;
    if (bid < 2 * G1_BLOCKS) {
        if (bid & 1) cnt_b = bid >> 1;
        else gemm_b = bid >> 1;
    } else {
        cnt_b = G1_BLOCKS + (bid - 2 * G1_BLOCKS);
    }

    if (cnt_b >= 0) {
        int t = cnt_b * 256 + tid;
        if (t < N_EDGES / 4) {
            int4 d = dst4[t];
            unsigned r0 = atomicAdd(&cnt[d.x], 1);
            unsigned r1 = atomicAdd(&cnt[d.y], 1);
            unsigned r2 = atomicAdd(&cnt[d.z], 1);
            unsigned r3 = atomicAdd(&cnt[d.w], 1);
            rank4[t] = make_uchar4((unsigned char)r0, (unsigned char)r1,
                                   (unsigned char)r2, (unsigned char)r3);
        }
        return;
    }

    // ---- gemm1 role ----
    int lane = tid & 63, w = tid >> 6;
    int wr = w >> 1, wc = w & 1;
    int row0 = gemm_b * 128;

    f32x4 acc[4][4];  // [fm][fn]
#pragma unroll
    for (int i = 0; i < 4; i++)
#pragma unroll
        for (int j = 0; j < 4; j++) acc[i][j] = (f32x4){0.f, 0.f, 0.f, 0.f};

    for (int ks = 0; ks < 8; ks++) {
        int k0 = ks * 32;
#pragma unroll
        for (int u = 0; u < 4; u++) {
            int slot = u * 256 + tid;          // 0..1023
            int r = slot >> 3, c4 = slot & 7;  // row, float4-slot
            int rr = min(row0 + r, N_NODES - 1);
            float4 v = *(const float4*)&X[(size_t)rr * F_INN + k0 + c4 * 4];
            uint2 p;
            p.x = bf16pack(v.x, v.y);
            p.y = bf16pack(v.z, v.w);
            *(uint2*)&xs[r * 32 + c4 * 4] = p;
        }
        bf16x8 bfr[4];
#pragma unroll
        for (int fn = 0; fn < 4; fn++) {
            uint4 t4 = Wf[((wc * 4 + fn) * 8 + ks) * 64 + lane];
            bfr[fn] = *(bf16x8*)&t4;
        }
        __syncthreads();
        bf16x8 afr[4];
#pragma unroll
        for (int fm = 0; fm < 4; fm++) {
            int r = wr * 64 + fm * 16 + (lane & 15);
            afr[fm] = *(const bf16x8*)&xs[r * 32 + ((lane >> 4) << 3)];
        }
#pragma unroll
        for (int fm = 0; fm < 4; fm++)
#pragma unroll
            for (int fn = 0; fn < 4; fn++)
                acc[fm][fn] = __builtin_amdgcn_mfma_f32_16x16x32_bf16(
                    bfr[fn], afr[fm], acc[fm][fn], 0, 0, 0);
        __syncthreads();
    }
    // epilogue: UNSCALED fp8 (dinv applied per-edge in gather1)
#pragma unroll
    for (int fm = 0; fm < 4; fm++) {
        int row = row0 + wr * 64 + fm * 16 + (lane & 15);
        if (row < N_NODES) {
            unsigned char* yrow = Y8 + (size_t)row * 128;
#pragma unroll
            for (int fn = 0; fn < 4; fn++) {
                int col = wc * 64 + fn * 16 + ((lane >> 4) << 2);
                unsigned o = fp8enc(acc[fm][fn][0])
                           | (fp8enc(acc[fm][fn][1]) << 8)
                           | (fp8enc(acc[fm][fn][2]) << 16)
                           | (fp8enc(acc[fm][fn][3]) << 24);
                *(unsigned*)&yrow[col] = o;
            }
        }
    }
}

// ------------- gather1: 2 nodes/wave, per-edge dinv FMA, unroll 8 -----------
__global__ __launch_bounds__(256) void k_gather1(const unsigned* __restrict__ Y32,
                                                 const int* __restrict__ rowptr,
                                                 const int* __restrict__ eidx,
                                                 const float* __restrict__ dinv,
                                                 const float* __restrict__ b1,
                                                 unsigned* __restrict__ Hb) {
    int wid = (blockIdx.x * blockDim.x + threadIdx.x) >> 6;
    int lane = threadIdx.x & 63;
    int half = lane >> 5, sl = lane & 31;
    int node = wid * 2 + half;
    if (node >= N_NODES) return;

    float s = dinv[node];
    float d0, d1, d2, d3;
    fp8dec4(Y32[(size_t)node * 32 + sl], d0, d1, d2, d3);  // self-loop
    float a0 = s * d0, a1 = s * d1, a2 = s * d2, a3 = s * d3;
    int beg = rowptr[node], end = rowptr[node + 1];
    int e = beg;
    int n8 = beg + ((end - beg) & ~7);
    for (; e < n8; e += 8) {
        int j[8];
#pragma unroll
        for (int u = 0; u < 8; u++) j[u] = eidx[e + u];
        unsigned v[8];
        float dv[8];
#pragma unroll
        for (int u = 0; u < 8; u++) {
            v[u] = Y32[(size_t)j[u] * 32 + sl];
            dv[u] = dinv[j[u]];
        }
#pragma unroll
        for (int u = 0; u < 8; u++) {
            fp8dec4(v[u], d0, d1, d2, d3);
            a0 = fmaf(dv[u], d0, a0);
            a1 = fmaf(dv[u], d1, a1);
            a2 = fmaf(dv[u], d2, a2);
            a3 = fmaf(dv[u], d3, a3);
        }
    }
    for (; e < end; e++) {
        int j = eidx[e];
        unsigned v = Y32[(size_t)j * 32 + sl];
        float dvv = dinv[j];
        fp8dec4(v, d0, d1, d2, d3);
        a0 = fmaf(dvv, d0, a0);
        a1 = fmaf(dvv, d1, a1);
        a2 = fmaf(dvv, d2, a2);
        a3 = fmaf(dvv, d3, a3);
    }
    float4 b = ((const float4*)b1)[sl];
    uint2 p;
    p.x = bf16pack(fmaxf(a0 * s + b.x, 0.f), fmaxf(a1 * s + b.y, 0.f));
    p.y = bf16pack(fmaxf(a2 * s + b.z, 0.f), fmaxf(a3 * s + b.w, 0.f));
    *(uint2*)&Hb[(size_t)node * 64 + sl * 2] = p;
}

// ------------- GEMM2: Y2_8 = fp8((H @ W2) * dinv[row]), row stride 64 B -----
__global__ __launch_bounds__(256) void k_gemm2(const unsigned* __restrict__ Hb,
                                               const float* __restrict__ W2,
                                               const float* __restrict__ dinv,
                                               unsigned char* __restrict__ Y2_8) {
    __shared__ __align__(16) float ws[128][48];
    int tid = threadIdx.x;
    for (int idx = tid; idx < 128 * 48; idx += 256) {
        int k = idx / 48, c = idx - k * 48;
        ws[k][c] = (c < NCLS) ? W2[k * NCLS + c] : 0.f;
    }
    __syncthreads();
    int row = blockIdx.x * 256 + tid;
    if (row >= N_NODES) return;
    float4 acc[12];
#pragma unroll
    for (int i = 0; i < 12; i++) acc[i] = make_float4(0.f, 0.f, 0.f, 0.f);
    const uint4* h4 = (const uint4*)(Hb + (size_t)row * 64);
    for (int kq = 0; kq < 16; kq++) {
        uint4 hv = h4[kq];
        float f[8];
        float2 f0 = bf16unpack(hv.x), f1 = bf16unpack(hv.y);
        float2 f2 = bf16unpack(hv.z), f3 = bf16unpack(hv.w);
        f[0] = f0.x; f[1] = f0.y; f[2] = f1.x; f[3] = f1.y;
        f[4] = f2.x; f[5] = f2.y; f[6] = f3.x; f[7] = f3.y;
#pragma unroll
        for (int u = 0; u < 8; u++) {
            float xv = f[u];
            int k = kq * 8 + u;
#pragma unroll
            for (int c = 0; c < 12; c++) {
                float4 w = *(const float4*)&ws[k][c * 4];
                acc[c].x += xv * w.x; acc[c].y += xv * w.y;
                acc[c].z += xv * w.z; acc[c].w += xv * w.w;
            }
        }
    }
    float s = dinv[row];
#pragma unroll
    for (int c = 0; c < 12; c++) {
        unsigned o = fp8enc(acc[c].x * s)
                   | (fp8enc(acc[c].y * s) << 8)
                   | (fp8enc(acc[c].z * s) << 16)
                   | (fp8enc(acc[c].w * s) << 24);
        *(unsigned*)&Y2_8[(size_t)row * 64 + c * 4] = o;
    }
}

// --- gather2 + log_softmax: 4 nodes/wave, 16 lanes/node, unroll 16 ----------
__global__ __launch_bounds__(256) void k_gather2(const unsigned* __restrict__ Y2_32,
                                                 const int* __restrict__ rowptr,
                                                 const int* __restrict__ eidx,
                                                 const float* __restrict__ dinv,
                                                 const float* __restrict__ b2,
                                                 float* __restrict__ Out) {
    int wid = (blockIdx.x * blockDim.x + threadIdx.x) >> 6;
    int lane = threadIdx.x & 63;
    int q = lane >> 4, sl = lane & 15;
    int node = wid * 4 + q;
    if (node >= N_NODES) return;

    float a0, a1, a2, a3;
    fp8dec4(Y2_32[(size_t)node * 16 + sl], a0, a1, a2, a3);  // self (pad lanes gated below)
    int beg = rowptr[node], end = rowptr[node + 1];
    int e = beg;
    int n16 = beg + ((end - beg) & ~15);
    for (; e < n16; e += 16) {
        int j[16];
#pragma unroll
        for (int u = 0; u < 16; u++) j[u] = eidx[e + u];
        unsigned v[16];
#pragma unroll
        for (int u = 0; u < 16; u++) v[u] = Y2_32[(size_t)j[u] * 16 + sl];
#pragma unroll
        for (int u = 0; u < 16; u++) {
            float d0, d1, d2, d3;
            fp8dec4(v[u], d0, d1, d2, d3);
            a0 += d0; a1 += d1; a2 += d2; a3 += d3;
        }
    }
    int n8 = e + ((end - e) & ~7);
    for (; e < n8; e += 8) {
        int j[8];
#pragma unroll
        for (int u = 0; u < 8; u++) j[u] = eidx[e + u];
        unsigned v[8];
#pragma unroll
        for (int u = 0; u < 8; u++) v[u] = Y2_32[(size_t)j[u] * 16 + sl];
#pragma unroll
        for (int u = 0; u < 8; u++) {
            float d0, d1, d2, d3;
            fp8dec4(v[u], d0, d1, d2, d3);
            a0 += d0; a1 += d1; a2 += d2; a3 += d3;
        }
    }
    for (; e < end; e++) {
        unsigned v = Y2_32[(size_t)eidx[e] * 16 + sl];
        float d0, d1, d2, d3;
        fp8dec4(v, d0, d1, d2, d3);
        a0 += d0; a1 += d1; a2 += d2; a3 += d3;
    }
    float s = dinv[node];
    int d0i = sl * 4;
    float v0 = (d0i + 0 < NCLS) ? a0 * s + b2[d0i + 0] : -INFINITY;
    float v1 = (d0i + 1 < NCLS) ? a1 * s + b2[d0i + 1] : -INFINITY;
    float v2 = (d0i + 2 < NCLS) ? a2 * s + b2[d0i + 2] : -INFINITY;
    float v3 = (d0i + 3 < NCLS) ? a3 * s + b2[d0i + 3] : -INFINITY;
    float m = fmaxf(fmaxf(v0, v1), fmaxf(v2, v3));
#pragma unroll
    for (int off = 1; off < 16; off <<= 1) m = fmaxf(m, __shfl_xor(m, off, 16));
    float ex = 0.f;
    ex += (d0i + 0 < NCLS) ? __expf(v0 - m) : 0.f;
    ex += (d0i + 1 < NCLS) ? __expf(v1 - m) : 0.f;
    ex += (d0i + 2 < NCLS) ? __expf(v2 - m) : 0.f;
    ex += (d0i + 3 < NCLS) ? __expf(v3 - m) : 0.f;
#pragma unroll
    for (int off = 1; off < 16; off <<= 1) ex += __shfl_xor(ex, off, 16);
    float l = __logf(ex);
    float* orow = Out + (size_t)node * NCLS;
    if (d0i + 0 < NCLS) orow[d0i + 0] = v0 - m - l;
    if (d0i + 1 < NCLS) orow[d0i + 1] = v1 - m - l;
    if (d0i + 2 < NCLS) orow[d0i + 2] = v2 - m - l;
    if (d0i + 3 < NCLS) orow[d0i + 3] = v3 - m - l;
}

extern "C" void kernel_launch(void* const* d_in, const int* in_sizes, int n_in,
                              void* d_out, int out_size, void* d_ws, size_t ws_size,
                              hipStream_t stream) {
    const float* x   = (const float*)d_in[0];
    const int*   ei  = (const int*)d_in[1];
    const float* W1  = (const float*)d_in[2];
    const float* b1  = (const float*)d_in[3];
    const float* W2  = (const float*)d_in[4];
    const float* b2  = (const float*)d_in[5];
    float* out = (float*)d_out;

    const int* src = ei;             // edge_index[0]
    const int* dst = ei + N_EDGES;   // edge_index[1]

    char* ws = (char*)d_ws;
    unsigned char*  y8   = (unsigned char*) (ws + 0);          // N*128 u8  (12.8 MB)
    unsigned*       hb   = (unsigned*)      (ws + 12800000);   // N*64 u32  (25.6 MB)
    unsigned char*  y2_8 = (unsigned char*) (ws + 38400000);   // N*64 u8   (6.4 MB)
    float*          dinv = (float*)         (ws + 44800000);   // N f32
    int*            cnt  = (int*)           (ws + 45200000);   // N int
    int*            rowptr=(int*)           (ws + 45600000);   // N+1 int
    int*            eidx = (int*)           (ws + 46000016);   // E int (6.4 MB)
    int*            bsum = (int*)           (ws + 52400016);   // 98 int
    int*            boff = (int*)           (ws + 52401040);   // 98 int
    unsigned char*  rank = (unsigned char*) (ws + 52402064);   // E u8 (1.6 MB)
    uint4*          wfrag= (uint4*)         (ws + 54002064);   // 64 KB

    // prologue (cheap): zero counters, pack W1 fragments
    k_init<<<(N_NODES + 255) / 256, 256, 0, stream>>>(cnt);
    k_prep<<<16, 256, 0, stream>>>(W1, wfrag);

    // fused: count+rank (atomic-throughput-bound) || gemm1 (MFMA-bound)
    k_fusedA<<<2 * G1_BLOCKS + (CNT_BLOCKS - G1_BLOCKS), 256, 0, stream>>>(
        x, wfrag, y8, (const int4*)dst, cnt, (uchar4*)rank);

    // scan -> rowptr, dinv
    k_scan_part<<<N_SBLOCKS, 256, 0, stream>>>(cnt, bsum);
    k_scan_top<<<1, 128, 0, stream>>>(bsum, boff);
    k_scan_final<<<N_SBLOCKS, 256, 0, stream>>>(cnt, boff, rowptr, dinv);

    // scatter (round-16 proven form)
    k_scatter<<<CNT_BLOCKS, 256, 0, stream>>>(
        (const int4*)src, (const int4*)dst, rowptr, (const uchar4*)rank, eidx);

    // layer 1 aggregation (per-edge dinv)
    k_gather1<<<((N_NODES + 1) / 2 * 64 + 255) / 256, 256, 0, stream>>>(
        (const unsigned*)y8, rowptr, eidx, dinv, b1, hb);

    // layer 2
    k_gemm2<<<(N_NODES + 255) / 256, 256, 0, stream>>>(hb, W2, dinv, y2_8);
    k_gather2<<<((N_NODES + 3) / 4 * 64 + 255) / 256, 256, 0, stream>>>(
        (const unsigned*)y2_8, rowptr, eidx, dinv, b2, out);
}

// Round 21
// 228.700 us; speedup vs baseline: 1.0910x; 1.0402x over previous
//
#include <hip/hip_runtime.h>
#include <math.h>

#define N_NODES 100000
#define N_EDGES 1600000
#define F_INN   256
#define HID     128
#define NCLS    47

#define SCAN_CHUNK 1024
#define N_SBLOCKS ((N_NODES + SCAN_CHUNK - 1) / SCAN_CHUNK)  // 98
#define G1_BLOCKS ((N_NODES + 127) / 128)                    // 782
#define CNT_BLOCKS ((N_EDGES / 4 + 255) / 256)               // 1563

typedef __attribute__((ext_vector_type(8))) short bf16x8;
typedef __attribute__((ext_vector_type(4))) float f32x4;
typedef __attribute__((ext_vector_type(2))) float f32x2;

// ---------------- bf16 helpers (RNE) ----------------
__device__ __forceinline__ unsigned bf16pack(float a, float b) {
    unsigned ua = __float_as_uint(a), ub = __float_as_uint(b);
    ua = (ua + 0x7FFFu + ((ua >> 16) & 1u)) >> 16;
    ub = (ub + 0x7FFFu + ((ub >> 16) & 1u)) >> 16;
    return ua | (ub << 16);
}
__device__ __forceinline__ float2 bf16unpack(unsigned v) {
    return make_float2(__uint_as_float(v << 16), __uint_as_float(v & 0xFFFF0000u));
}

// ---------------- fp8 e4m3 (OCP) helpers ------------------------------------
__device__ __forceinline__ unsigned fp8enc(float f) {
    unsigned u = __float_as_uint(f);
    unsigned r = u + 0x7FFFFu + ((u >> 20) & 1u);  // RNE into bit 20
    unsigned exp = (r >> 23) & 0xFFu;
    unsigned s = (u >> 24) & 0x80u;
    if (exp < 121u) return s;                      // flush to +-0
    if (exp > 135u) return s | 0x7Eu;              // saturate (won't occur)
    return s | ((exp - 120u) << 3) | ((r >> 20) & 7u);
}

#if __has_builtin(__builtin_amdgcn_cvt_pk_f32_fp8) && __has_builtin(__builtin_amdgcn_cvt_f32_fp8)
#define HWCVT 1
#endif

// decode 4 fp8 (one u32) -> 4 f32
__device__ __forceinline__ void fp8dec4(unsigned v, float& a, float& b, float& c, float& d) {
#ifdef HWCVT
    f32x2 lo = __builtin_amdgcn_cvt_pk_f32_fp8((int)v, false);
    f32x2 hi = __builtin_amdgcn_cvt_pk_f32_fp8((int)v, true);
    a = lo[0]; b = lo[1]; c = hi[0]; d = hi[1];
#else
    unsigned p0 = v & 0xFFFFu, p1 = v >> 16;
    unsigned m0 = ((p0 & 0x7Fu) << 4) + ((p0 & 0x7F00u) << 12) + 0x3C003C00u;
    unsigned g0 = ((p0 & 0x80u) << 8) | ((p0 & 0x8000u) << 16);
    unsigned b0 = m0 | g0;
    unsigned m1 = ((p1 & 0x7Fu) << 4) + ((p1 & 0x7F00u) << 12) + 0x3C003C00u;
    unsigned g1 = ((p1 & 0x80u) << 8) | ((p1 & 0x8000u) << 16);
    unsigned b1_ = m1 | g1;
    a = __uint_as_float(b0 << 16); b = __uint_as_float(b0 & 0xFFFF0000u);
    c = __uint_as_float(b1_ << 16); d = __uint_as_float(b1_ & 0xFFFF0000u);
#endif
}

// ---------------- CSR build ----------------
__global__ void k_init(int* cnt) {
    int i = blockIdx.x * blockDim.x + threadIdx.x;
    if (i < N_NODES) cnt[i] = 0;
}

__global__ __launch_bounds__(256) void k_scan_part(const int* __restrict__ cnt,
                                                   int* __restrict__ bsum) {
    int b = blockIdx.x, t = threadIdx.x;
    int base = b * SCAN_CHUNK;
    int local = 0;
#pragma unroll
    for (int u = 0; u < 4; u++) {
        int idx = base + u * 256 + t;
        if (idx < N_NODES) local += cnt[idx];
    }
#pragma unroll
    for (int off = 32; off >= 1; off >>= 1) local += __shfl_down(local, off, 64);
    __shared__ int red[4];
    if ((t & 63) == 0) red[t >> 6] = local;
    __syncthreads();
    if (t == 0) bsum[b] = red[0] + red[1] + red[2] + red[3];
}

__global__ void k_scan_top(const int* __restrict__ bsum, int* __restrict__ boff) {
    __shared__ int s[128];
    int t = threadIdx.x;
    int v = (t < N_SBLOCKS) ? bsum[t] : 0;
    s[t] = v;
    __syncthreads();
    for (int off = 1; off < 128; off <<= 1) {
        int u = (t >= off) ? s[t - off] : 0;
        __syncthreads();
        s[t] += u;
        __syncthreads();
    }
    if (t < N_SBLOCKS) boff[t] = s[t] - v;  // exclusive
}

__global__ __launch_bounds__(256) void k_scan_final(const int* __restrict__ cnt,
                                                    const int* __restrict__ boff,
                                                    int* __restrict__ rowptr,
                                                    float* __restrict__ dinv) {
    __shared__ int tsum[256];
    int b = blockIdx.x, t = threadIdx.x;
    int base = b * SCAN_CHUNK + t * 4;
    int c[4];
    int local = 0;
#pragma unroll
    for (int u = 0; u < 4; u++) {
        int idx = base + u;
        c[u] = (idx < N_NODES) ? cnt[idx] : 0;
        local += c[u];
    }
    tsum[t] = local;
    __syncthreads();
    for (int off = 1; off < 256; off <<= 1) {
        int u = (t >= off) ? tsum[t - off] : 0;
        __syncthreads();
        tsum[t] += u;
        __syncthreads();
    }
    int run = boff[b] + tsum[t] - local;
#pragma unroll
    for (int u = 0; u < 4; u++) {
        int idx = base + u;
        if (idx < N_NODES) {
            rowptr[idx] = run;
            dinv[idx] = rsqrtf((float)c[u] + 1.0f);  // +1 self-loop
            run += c[u];
        }
    }
    if (b == 0 && t == 0) rowptr[N_NODES] = N_EDGES;
}

// atomic-free scatter, 4 edges/thread (round-16 proven form)
__global__ __launch_bounds__(256) void k_scatter(const int4* __restrict__ src4,
                                                 const int4* __restrict__ dst4,
                                                 const int* __restrict__ rowptr,
                                                 const uchar4* __restrict__ rank4,
                                                 int* __restrict__ eidx) {
    int t = blockIdx.x * blockDim.x + threadIdx.x;
    if (t < N_EDGES / 4) {
        int4 s = src4[t];
        int4 d = dst4[t];
        uchar4 r = rank4[t];
        int p0 = rowptr[d.x] + (int)r.x;
        int p1 = rowptr[d.y] + (int)r.y;
        int p2 = rowptr[d.z] + (int)r.z;
        int p3 = rowptr[d.w] + (int)r.w;
        eidx[p0] = s.x;
        eidx[p1] = s.y;
        eidx[p2] = s.z;
        eidx[p3] = s.w;
    }
}

// ---- prep: W1 (256x128 f32) -> MFMA-fragment-ordered bf16 ------------------
__global__ __launch_bounds__(256) void k_prep(const float* __restrict__ W1,
                                              uint4* __restrict__ Wf) {
    int g = blockIdx.x * blockDim.x + threadIdx.x;  // 0..4095
    if (g >= 4096) return;
    int l = g & 63;
    int kst = (g >> 6) & 7;
    int nt = g >> 9;
    int n = nt * 16 + (l & 15);
    int kb = kst * 32 + ((l >> 4) << 3);
    float v[8];
#pragma unroll
    for (int j = 0; j < 8; j++) v[j] = W1[(size_t)(kb + j) * HID + n];
    uint4 o;
    o.x = bf16pack(v[0], v[1]);
    o.y = bf16pack(v[2], v[3]);
    o.z = bf16pack(v[4], v[5]);
    o.w = bf16pack(v[6], v[7]);
    Wf[g] = o;
}

// ---- fused: GEMM1 (MFMA, unscaled fp8 out) || count+rank -------------------
__global__ __launch_bounds__(256) void k_fusedA(const float* __restrict__ X,
                                                const uint4* __restrict__ Wf,
                                                unsigned char* __restrict__ Y8,
                                                const int4* __restrict__ dst4,
                                                int* cnt,
                                                uchar4* __restrict__ rank4) {
    __shared__ __align__(16) unsigned short xs[128 * 32];
    int bid = blockIdx.x;
    int tid = threadIdx.x;

    // role assignment: bids [0, 2*G1): even=gemm1, odd=count; rest=count
    int gemm_b = -1, cnt_b = -1;
    if (bid < 2 * G1_BLOCKS) {
        if (bid & 1) cnt_b = bid >> 1;
        else gemm_b = bid >> 1;
    } else {
        cnt_b = G1_BLOCKS + (bid - 2 * G1_BLOCKS);
    }

    if (cnt_b >= 0) {
        int t = cnt_b * 256 + tid;
        if (t < N_EDGES / 4) {
            int4 d = dst4[t];
            unsigned r0 = atomicAdd(&cnt[d.x], 1);
            unsigned r1 = atomicAdd(&cnt[d.y], 1);
            unsigned r2 = atomicAdd(&cnt[d.z], 1);
            unsigned r3 = atomicAdd(&cnt[d.w], 1);
            rank4[t] = make_uchar4((unsigned char)r0, (unsigned char)r1,
                                   (unsigned char)r2, (unsigned char)r3);
        }
        return;
    }

    // ---- gemm1 role ----
    int lane = tid & 63, w = tid >> 6;
    int wr = w >> 1, wc = w & 1;
    int row0 = gemm_b * 128;

    f32x4 acc[4][4];  // [fm][fn]
#pragma unroll
    for (int i = 0; i < 4; i++)
#pragma unroll
        for (int j = 0; j < 4; j++) acc[i][j] = (f32x4){0.f, 0.f, 0.f, 0.f};

    for (int ks = 0; ks < 8; ks++) {
        int k0 = ks * 32;
#pragma unroll
        for (int u = 0; u < 4; u++) {
            int slot = u * 256 + tid;          // 0..1023
            int r = slot >> 3, c4 = slot & 7;  // row, float4-slot
            int rr = min(row0 + r, N_NODES - 1);
            float4 v = *(const float4*)&X[(size_t)rr * F_INN + k0 + c4 * 4];
            uint2 p;
            p.x = bf16pack(v.x, v.y);
            p.y = bf16pack(v.z, v.w);
            *(uint2*)&xs[r * 32 + c4 * 4] = p;
        }
        bf16x8 bfr[4];
#pragma unroll
        for (int fn = 0; fn < 4; fn++) {
            uint4 t4 = Wf[((wc * 4 + fn) * 8 + ks) * 64 + lane];
            bfr[fn] = *(bf16x8*)&t4;
        }
        __syncthreads();
        bf16x8 afr[4];
#pragma unroll
        for (int fm = 0; fm < 4; fm++) {
            int r = wr * 64 + fm * 16 + (lane & 15);
            afr[fm] = *(const bf16x8*)&xs[r * 32 + ((lane >> 4) << 3)];
        }
#pragma unroll
        for (int fm = 0; fm < 4; fm++)
#pragma unroll
            for (int fn = 0; fn < 4; fn++)
                acc[fm][fn] = __builtin_amdgcn_mfma_f32_16x16x32_bf16(
                    bfr[fn], afr[fm], acc[fm][fn], 0, 0, 0);
        __syncthreads();
    }
    // epilogue: UNSCALED fp8 (dinv applied per-edge in gather1)
#pragma unroll
    for (int fm = 0; fm < 4; fm++) {
        int row = row0 + wr * 64 + fm * 16 + (lane & 15);
        if (row < N_NODES) {
            unsigned char* yrow = Y8 + (size_t)row * 128;
#pragma unroll
            for (int fn = 0; fn < 4; fn++) {
                int col = wc * 64 + fn * 16 + ((lane >> 4) << 2);
                unsigned o = fp8enc(acc[fm][fn][0])
                           | (fp8enc(acc[fm][fn][1]) << 8)
                           | (fp8enc(acc[fm][fn][2]) << 16)
                           | (fp8enc(acc[fm][fn][3]) << 24);
                *(unsigned*)&yrow[col] = o;
            }
        }
    }
}

// ---- gather1: 4 nodes/wave, 16 lanes/node, uint2 (8 fp8)/lane, unroll 8 ----
__global__ __launch_bounds__(256) void k_gather1(const unsigned* __restrict__ Y32,
                                                 const int* __restrict__ rowptr,
                                                 const int* __restrict__ eidx,
                                                 const float* __restrict__ dinv,
                                                 const float* __restrict__ b1,
                                                 unsigned* __restrict__ Hb) {
    int wid = (blockIdx.x * blockDim.x + threadIdx.x) >> 6;
    int lane = threadIdx.x & 63;
    int g = lane >> 4, sl = lane & 15;
    int node = wid * 4 + g;
    if (node >= N_NODES) return;

    const uint2* yp = (const uint2*)Y32;  // row stride = 16 uint2 (128 B)
    float s = dinv[node];
    uint2 vs = yp[(size_t)node * 16 + sl];  // self-loop (unscaled)
    float d0, d1, d2, d3, d4, d5, d6, d7;
    fp8dec4(vs.x, d0, d1, d2, d3);
    fp8dec4(vs.y, d4, d5, d6, d7);
    float a0 = s * d0, a1 = s * d1, a2 = s * d2, a3 = s * d3;
    float a4 = s * d4, a5 = s * d5, a6 = s * d6, a7 = s * d7;

    int beg = rowptr[node], end = rowptr[node + 1];
    int e = beg;
    int n8 = beg + ((end - beg) & ~7);
    for (; e < n8; e += 8) {
        int j[8];
#pragma unroll
        for (int u = 0; u < 8; u++) j[u] = eidx[e + u];
        uint2 v[8];
        float dv[8];
#pragma unroll
        for (int u = 0; u < 8; u++) {
            v[u] = yp[(size_t)j[u] * 16 + sl];
            dv[u] = dinv[j[u]];
        }
#pragma unroll
        for (int u = 0; u < 8; u++) {
            fp8dec4(v[u].x, d0, d1, d2, d3);
            fp8dec4(v[u].y, d4, d5, d6, d7);
            a0 = fmaf(dv[u], d0, a0); a1 = fmaf(dv[u], d1, a1);
            a2 = fmaf(dv[u], d2, a2); a3 = fmaf(dv[u], d3, a3);
            a4 = fmaf(dv[u], d4, a4); a5 = fmaf(dv[u], d5, a5);
            a6 = fmaf(dv[u], d6, a6); a7 = fmaf(dv[u], d7, a7);
        }
    }
    for (; e < end; e++) {
        int j = eidx[e];
        uint2 v = yp[(size_t)j * 16 + sl];
        float dvv = dinv[j];
        fp8dec4(v.x, d0, d1, d2, d3);
        fp8dec4(v.y, d4, d5, d6, d7);
        a0 = fmaf(dvv, d0, a0); a1 = fmaf(dvv, d1, a1);
        a2 = fmaf(dvv, d2, a2); a3 = fmaf(dvv, d3, a3);
        a4 = fmaf(dvv, d4, a4); a5 = fmaf(dvv, d5, a5);
        a6 = fmaf(dvv, d6, a6); a7 = fmaf(dvv, d7, a7);
    }
    float4 bA = ((const float4*)b1)[sl * 2];
    float4 bB = ((const float4*)b1)[sl * 2 + 1];
    uint4 p;
    p.x = bf16pack(fmaxf(a0 * s + bA.x, 0.f), fmaxf(a1 * s + bA.y, 0.f));
    p.y = bf16pack(fmaxf(a2 * s + bA.z, 0.f), fmaxf(a3 * s + bA.w, 0.f));
    p.z = bf16pack(fmaxf(a4 * s + bB.x, 0.f), fmaxf(a5 * s + bB.y, 0.f));
    p.w = bf16pack(fmaxf(a6 * s + bB.z, 0.f), fmaxf(a7 * s + bB.w, 0.f));
    ((uint4*)Hb)[(size_t)node * 16 + sl] = p;
}

// ------------- GEMM2: Y2_8 = fp8((H @ W2) * dinv[row]), row stride 64 B -----
__global__ __launch_bounds__(256) void k_gemm2(const unsigned* __restrict__ Hb,
                                               const float* __restrict__ W2,
                                               const float* __restrict__ dinv,
                                               unsigned char* __restrict__ Y2_8) {
    __shared__ __align__(16) float ws[128][48];
    int tid = threadIdx.x;
    for (int idx = tid; idx < 128 * 48; idx += 256) {
        int k = idx / 48, c = idx - k * 48;
        ws[k][c] = (c < NCLS) ? W2[k * NCLS + c] : 0.f;
    }
    __syncthreads();
    int row = blockIdx.x * 256 + tid;
    if (row >= N_NODES) return;
    float4 acc[12];
#pragma unroll
    for (int i = 0; i < 12; i++) acc[i] = make_float4(0.f, 0.f, 0.f, 0.f);
    const uint4* h4 = (const uint4*)(Hb + (size_t)row * 64);
    for (int kq = 0; kq < 16; kq++) {
        uint4 hv = h4[kq];
        float f[8];
        float2 f0 = bf16unpack(hv.x), f1 = bf16unpack(hv.y);
        float2 f2 = bf16unpack(hv.z), f3 = bf16unpack(hv.w);
        f[0] = f0.x; f[1] = f0.y; f[2] = f1.x; f[3] = f1.y;
        f[4] = f2.x; f[5] = f2.y; f[6] = f3.x; f[7] = f3.y;
#pragma unroll
        for (int u = 0; u < 8; u++) {
            float xv = f[u];
            int k = kq * 8 + u;
#pragma unroll
            for (int c = 0; c < 12; c++) {
                float4 w = *(const float4*)&ws[k][c * 4];
                acc[c].x += xv * w.x; acc[c].y += xv * w.y;
                acc[c].z += xv * w.z; acc[c].w += xv * w.w;
            }
        }
    }
    float s = dinv[row];
#pragma unroll
    for (int c = 0; c < 12; c++) {
        unsigned o = fp8enc(acc[c].x * s)
                   | (fp8enc(acc[c].y * s) << 8)
                   | (fp8enc(acc[c].z * s) << 16)
                   | (fp8enc(acc[c].w * s) << 24);
        *(unsigned*)&Y2_8[(size_t)row * 64 + c * 4] = o;
    }
}

// --- gather2 + log_softmax: 8 nodes/wave, 8 lanes/node, uint2/lane ----------
__global__ __launch_bounds__(256) void k_gather2(const unsigned* __restrict__ Y2_32,
                                                 const int* __restrict__ rowptr,
                                                 const int* __restrict__ eidx,
                                                 const float* __restrict__ dinv,
                                                 const float* __restrict__ b2,
                                                 float* __restrict__ Out) {
    int wid = (blockIdx.x * blockDim.x + threadIdx.x) >> 6;
    int lane = threadIdx.x & 63;
    int g = lane >> 3, sl = lane & 7;
    int node = wid * 8 + g;
    if (node >= N_NODES) return;

    const uint2* yp = (const uint2*)Y2_32;  // row stride = 8 uint2 (64 B)
    uint2 vs = yp[(size_t)node * 8 + sl];   // self (pad lanes gated below)
    float a0, a1, a2, a3, a4, a5, a6, a7;
    fp8dec4(vs.x, a0, a1, a2, a3);
    fp8dec4(vs.y, a4, a5, a6, a7);

    int beg = rowptr[node], end = rowptr[node + 1];
    int e = beg;
    int n8 = beg + ((end - beg) & ~7);
    for (; e < n8; e += 8) {
        int j[8];
#pragma unroll
        for (int u = 0; u < 8; u++) j[u] = eidx[e + u];
        uint2 v[8];
#pragma unroll
        for (int u = 0; u < 8; u++) v[u] = yp[(size_t)j[u] * 8 + sl];
#pragma unroll
        for (int u = 0; u < 8; u++) {
            float d0, d1, d2, d3, d4, d5, d6, d7;
            fp8dec4(v[u].x, d0, d1, d2, d3);
            fp8dec4(v[u].y, d4, d5, d6, d7);
            a0 += d0; a1 += d1; a2 += d2; a3 += d3;
            a4 += d4; a5 += d5; a6 += d6; a7 += d7;
        }
    }
    for (; e < end; e++) {
        uint2 v = yp[(size_t)eidx[e] * 8 + sl];
        float d0, d1, d2, d3, d4, d5, d6, d7;
        fp8dec4(v.x, d0, d1, d2, d3);
        fp8dec4(v.y, d4, d5, d6, d7);
        a0 += d0; a1 += d1; a2 += d2; a3 += d3;
        a4 += d4; a5 += d5; a6 += d6; a7 += d7;
    }
    float s = dinv[node];
    int d0i = sl * 8;
    float vv[8];
    float aa[8] = {a0, a1, a2, a3, a4, a5, a6, a7};
#pragma unroll
    for (int k = 0; k < 8; k++)
        vv[k] = (d0i + k < NCLS) ? aa[k] * s + b2[d0i + k] : -INFINITY;
    float m = vv[0];
#pragma unroll
    for (int k = 1; k < 8; k++) m = fmaxf(m, vv[k]);
#pragma unroll
    for (int off = 1; off < 8; off <<= 1) m = fmaxf(m, __shfl_xor(m, off, 8));
    float ex = 0.f;
#pragma unroll
    for (int k = 0; k < 8; k++) ex += (d0i + k < NCLS) ? __expf(vv[k] - m) : 0.f;
#pragma unroll
    for (int off = 1; off < 8; off <<= 1) ex += __shfl_xor(ex, off, 8);
    float l = __logf(ex);
    float* orow = Out + (size_t)node * NCLS;
#pragma unroll
    for (int k = 0; k < 8; k++)
        if (d0i + k < NCLS) orow[d0i + k] = vv[k] - m - l;
}

extern "C" void kernel_launch(void* const* d_in, const int* in_sizes, int n_in,
                              void* d_out, int out_size, void* d_ws, size_t ws_size,
                              hipStream_t stream) {
    const float* x   = (const float*)d_in[0];
    const int*   ei  = (const int*)d_in[1];
    const float* W1  = (const float*)d_in[2];
    const float* b1  = (const float*)d_in[3];
    const float* W2  = (const float*)d_in[4];
    const float* b2  = (const float*)d_in[5];
    float* out = (float*)d_out;

    const int* src = ei;             // edge_index[0]
    const int* dst = ei + N_EDGES;   // edge_index[1]

    char* ws = (char*)d_ws;
    unsigned char*  y8   = (unsigned char*) (ws + 0);          // N*128 u8  (12.8 MB)
    unsigned*       hb   = (unsigned*)      (ws + 12800000);   // N*64 u32  (25.6 MB)
    unsigned char*  y2_8 = (unsigned char*) (ws + 38400000);   // N*64 u8   (6.4 MB)
    float*          dinv = (float*)         (ws + 44800000);   // N f32
    int*            cnt  = (int*)           (ws + 45200000);   // N int
    int*            rowptr=(int*)           (ws + 45600000);   // N+1 int
    int*            eidx = (int*)           (ws + 46000016);   // E int (6.4 MB)
    int*            bsum = (int*)           (ws + 52400016);   // 98 int
    int*            boff = (int*)           (ws + 52401040);   // 98 int
    unsigned char*  rank = (unsigned char*) (ws + 52402064);   // E u8 (1.6 MB)
    uint4*          wfrag= (uint4*)         (ws + 54002064);   // 64 KB

    // prologue (cheap): zero counters, pack W1 fragments
    k_init<<<(N_NODES + 255) / 256, 256, 0, stream>>>(cnt);
    k_prep<<<16, 256, 0, stream>>>(W1, wfrag);

    // fused: count+rank (atomic-throughput-bound) || gemm1 (MFMA-bound)
    k_fusedA<<<2 * G1_BLOCKS + (CNT_BLOCKS - G1_BLOCKS), 256, 0, stream>>>(
        x, wfrag, y8, (const int4*)dst, cnt, (uchar4*)rank);

    // scan -> rowptr, dinv
    k_scan_part<<<N_SBLOCKS, 256, 0, stream>>>(cnt, bsum);
    k_scan_top<<<1, 128, 0, stream>>>(bsum, boff);
    k_scan_final<<<N_SBLOCKS, 256, 0, stream>>>(cnt, boff, rowptr, dinv);

    // scatter (round-16 proven form)
    k_scatter<<<CNT_BLOCKS, 256, 0, stream>>>(
        (const int4*)src, (const int4*)dst, rowptr, (const uchar4*)rank, eidx);

    // layer 1 aggregation: 4 nodes per wave
    k_gather1<<<((N_NODES + 3) / 4 * 64 + 255) / 256, 256, 0, stream>>>(
        (const unsigned*)y8, rowptr, eidx, dinv, b1, hb);

    // layer 2
    k_gemm2<<<(N_NODES + 255) / 256, 256, 0, stream>>>(hb, W2, dinv, y2_8);
    // 8 nodes per wave
    k_gather2<<<((N_NODES + 7) / 8 * 64 + 255) / 256, 256, 0, stream>>>(
        (const unsigned*)y2_8, rowptr, eidx, dinv, b2, out);
}